// Round 4
// baseline (357.481 us; speedup 1.0000x reference)
//
#include <hip/hip_runtime.h>
#include <math.h>

#define T_DIM 2048
#define N_DIM 64
#define E_DIM 1024
#define A_DIM 256

typedef __bf16 bf16x8 __attribute__((ext_vector_type(8)));
typedef float f32x4 __attribute__((ext_vector_type(4)));

__device__ __forceinline__ float tanh_fast(float x) {
    float xc = fminf(fmaxf(x, -15.f), 15.f);
    float e = __expf(2.f * xc);
    return (e - 1.f) / (e + 1.f);
}

// ---- W_e fp32 [A,E] -> bf16, permuted: unit (kt,g,a) = W_e[a][kt*32+g*8..+8]
// at offset ((kt*4+g)*256+a)*8
__global__ __launch_bounds__(256) void convert_W(const float* __restrict__ W_e,
                                                 __bf16* __restrict__ Wp) {
    const int uid = blockIdx.x * 256 + threadIdx.x;  // 32768 units
    const int a = uid >> 7;
    const int c = uid & 127;  // c = kt*4+g
    const float4* src = (const float4*)(W_e + (size_t)a * E_DIM + c * 8);
    float4 x0 = src[0], x1 = src[1];
    bf16x8 o;
    o[0] = (__bf16)x0.x; o[1] = (__bf16)x0.y; o[2] = (__bf16)x0.z; o[3] = (__bf16)x0.w;
    o[4] = (__bf16)x1.x; o[5] = (__bf16)x1.y; o[6] = (__bf16)x1.z; o[7] = (__bf16)x1.w;
    *(bf16x8*)(Wp + ((size_t)c * 256 + a) * 8) = o;
}

// ---------------- d_proj[n][a] = dot(dec_h[n,:], W_d[a,:]) ----------------
__global__ __launch_bounds__(256) void dproj_kernel(
    const float* __restrict__ dec_h, const float* __restrict__ W_d,
    float* __restrict__ d_proj) {
    __shared__ float dec[E_DIM];
    const int n = blockIdx.x;
    const int tid = threadIdx.x;
    reinterpret_cast<float4*>(dec)[tid] =
        reinterpret_cast<const float4*>(dec_h + (size_t)n * E_DIM)[tid];
    __syncthreads();
    const float* w = W_d + (size_t)tid * E_DIM;
    float acc = 0.f;
#pragma unroll 4
    for (int e = 0; e < E_DIM; e += 4) {
        float4 wv = *reinterpret_cast<const float4*>(w + e);
        acc = fmaf(wv.x, dec[e], acc);
        acc = fmaf(wv.y, dec[e + 1], acc);
        acc = fmaf(wv.z, dec[e + 2], acc);
        acc = fmaf(wv.w, dec[e + 3], acc);
    }
    d_proj[n * A_DIM + tid] = acc;
}

// ---- fused scores: 64x256 tile, BK=32, 256 thr = 4 waves (a-quadrants).
// A via LDS dbuf (1 barrier/iter); B frags direct from L2; emits bf16 enc copy.
__global__ __launch_bounds__(256, 4) void scores_mfma(
    const float* __restrict__ enc, const __bf16* __restrict__ Wp,
    const float* __restrict__ dproj, const float* __restrict__ v,
    float* __restrict__ scores, __bf16* __restrict__ enc_bf) {
    __shared__ __bf16 Ab[2][2048];  // [g][row] bf16x8 units, 2 x 4 KB

    const int tid = threadIdx.x;
    const int m0 = blockIdx.x * 64;
    const int wn = tid >> 6;
    const int lane = tid & 63;
    const int lr = lane & 15, lg = lane >> 4;

    f32x4 acc[4][4];
#pragma unroll
    for (int i = 0; i < 4; ++i)
#pragma unroll
        for (int j = 0; j < 4; ++j) acc[i][j] = (f32x4){0.f, 0.f, 0.f, 0.f};

    const int arow = tid >> 2, ag = tid & 3;
    const float* encA = enc + (size_t)(m0 + arow) * E_DIM + ag * 8;
    __bf16* ebase =
        enc_bf ? enc_bf + (size_t)(m0 + arow) * E_DIM + ag * 8 : nullptr;
    const bf16x8* WpV = (const bf16x8*)Wp;
    const int bidx = lg * 256 + wn * 64 + lr;  // B frag base within k-tile

    // prologue: stage kt=0
    {
        float4 a0 = *(const float4*)encA;
        float4 a1 = *(const float4*)(encA + 4);
        bf16x8 p;
        p[0] = (__bf16)a0.x; p[1] = (__bf16)a0.y; p[2] = (__bf16)a0.z; p[3] = (__bf16)a0.w;
        p[4] = (__bf16)a1.x; p[5] = (__bf16)a1.y; p[6] = (__bf16)a1.z; p[7] = (__bf16)a1.w;
        ((bf16x8*)Ab[0])[ag * 64 + arow] = p;
        if (ebase) *(bf16x8*)ebase = p;
    }
    __syncthreads();

    float4 aR0, aR1;
    for (int kt = 0; kt < 32; ++kt) {
        const int cur = kt & 1;
        // B fragments for current kt — from L2, issued first so the MFMA
        // vmcnt-wait leaves the A prefetch in flight
        const bf16x8* pB = WpV + (size_t)kt * 1024 + bidx;
        bf16x8 bfr0 = pB[0];
        bf16x8 bfr1 = pB[16];
        bf16x8 bfr2 = pB[32];
        bf16x8 bfr3 = pB[48];
        if (kt < 31) {  // prefetch next A tile into registers
            const float* pA = encA + (kt + 1) * 32;
            aR0 = *(const float4*)pA;
            aR1 = *(const float4*)(pA + 4);
        }
        const bf16x8* As = (const bf16x8*)Ab[cur];
#pragma unroll
        for (int fm = 0; fm < 4; ++fm) {
            bf16x8 af = As[lg * 64 + fm * 16 + lr];
            acc[fm][0] = __builtin_amdgcn_mfma_f32_16x16x32_bf16(af, bfr0, acc[fm][0], 0, 0, 0);
            acc[fm][1] = __builtin_amdgcn_mfma_f32_16x16x32_bf16(af, bfr1, acc[fm][1], 0, 0, 0);
            acc[fm][2] = __builtin_amdgcn_mfma_f32_16x16x32_bf16(af, bfr2, acc[fm][2], 0, 0, 0);
            acc[fm][3] = __builtin_amdgcn_mfma_f32_16x16x32_bf16(af, bfr3, acc[fm][3], 0, 0, 0);
        }
        if (kt < 31) {  // cvt + write-late into the other buffer (+ enc_bf)
            bf16x8 p;
            p[0] = (__bf16)aR0.x; p[1] = (__bf16)aR0.y; p[2] = (__bf16)aR0.z; p[3] = (__bf16)aR0.w;
            p[4] = (__bf16)aR1.x; p[5] = (__bf16)aR1.y; p[6] = (__bf16)aR1.z; p[7] = (__bf16)aR1.w;
            ((bf16x8*)Ab[cur ^ 1])[ag * 64 + arow] = p;
            if (ebase) *(bf16x8*)(ebase + (kt + 1) * 32) = p;
        }
        __syncthreads();  // single barrier: publishes buf^1, closes reads of cur
    }

    // ---- epilogue: tanh(e+d) dot v, reduce over a ----
    float vv[4];
#pragma unroll
    for (int fn = 0; fn < 4; ++fn) vv[fn] = v[wn * 64 + fn * 16 + lr];
    float* red = (float*)Ab[0];  // 1 KB, safe after final barrier
#pragma unroll
    for (int fm = 0; fm < 4; ++fm) {
#pragma unroll
        for (int reg = 0; reg < 4; ++reg) {
            const int r = fm * 16 + lg * 4 + reg;  // row in tile == n
            float p = 0.f;
#pragma unroll
            for (int fn = 0; fn < 4; ++fn) {
                const int a = wn * 64 + fn * 16 + lr;
                p = fmaf(vv[fn], tanh_fast(acc[fm][fn][reg] + dproj[r * A_DIM + a]), p);
            }
            p += __shfl_xor(p, 1);
            p += __shfl_xor(p, 2);
            p += __shfl_xor(p, 4);
            p += __shfl_xor(p, 8);
            if (lr == 0) red[wn * 64 + r] = p;
        }
    }
    __syncthreads();
    if (tid < 64)
        scores[m0 + tid] =
            red[tid] + red[64 + tid] + red[128 + tid] + red[192 + tid];
}

// ---------------- softmax over t per column n ----------------
__global__ __launch_bounds__(256) void softmax_kernel(
    const float* __restrict__ scores, float* __restrict__ alpha) {
    __shared__ float red[256];
    const int n = blockIdx.x;
    const int tid = threadIdx.x;
    float m = -3.4e38f;
    for (int t = tid; t < T_DIM; t += 256)
        m = fmaxf(m, scores[t * N_DIM + n]);
    red[tid] = m;
    __syncthreads();
    for (int s = 128; s; s >>= 1) {
        if (tid < s) red[tid] = fmaxf(red[tid], red[tid + s]);
        __syncthreads();
    }
    m = red[0];
    __syncthreads();
    float sum = 0.f;
    for (int t = tid; t < T_DIM; t += 256)
        sum += expf(scores[t * N_DIM + n] - m);
    red[tid] = sum;
    __syncthreads();
    for (int s = 128; s; s >>= 1) {
        if (tid < s) red[tid] += red[tid + s];
        __syncthreads();
    }
    const float inv = 1.f / red[0];
    for (int t = tid; t < T_DIM; t += 256)
        alpha[t * N_DIM + n] = expf(scores[t * N_DIM + n] - m) * inv;
}

// ---- ctx partials from bf16 enc copy (reversed chunks -> L3-hot first) ----
__global__ __launch_bounds__(256) void ctx_partial_bf(
    const __bf16* __restrict__ enc_bf, const float* __restrict__ alpha,
    float* __restrict__ out, int tlen, int nchunk) {
    __shared__ float als[128];
    __shared__ float fold[1024];
    const int n = blockIdx.x;
    const int tc = blockIdx.y;
    const int tid = threadIdx.x;
    const int t0 = (nchunk - 1 - tc) * tlen;  // high-t chunks first
    if (tid < tlen) als[tid] = alpha[(t0 + tid) * N_DIM + n];
    __syncthreads();
    const int half = tid >> 7;   // processes t-pairs
    const int es = tid & 127;    // e-slot: elems es*8..+8
    float acc[8];
#pragma unroll
    for (int j = 0; j < 8; ++j) acc[j] = 0.f;
    for (int i = 0; i < tlen; i += 2) {
        const int t = t0 + i + half;
        const float al = als[i + half];
        bf16x8 ev = *(const bf16x8*)(enc_bf + ((size_t)t * N_DIM + n) * E_DIM + es * 8);
#pragma unroll
        for (int j = 0; j < 8; ++j) acc[j] = fmaf(al, (float)ev[j], acc[j]);
    }
    if (half == 1) {
#pragma unroll
        for (int j = 0; j < 8; ++j) fold[es * 8 + j] = acc[j];
    }
    __syncthreads();
    if (half == 0) {
        float* dst = out + ((size_t)tc * N_DIM + n) * E_DIM + es * 8;
#pragma unroll
        for (int j = 0; j < 8; ++j) dst[j] = acc[j] + fold[es * 8 + j];
    }
}

// fallback: fp32 ctx in one pass (only if ws too small for enc_bf)
__global__ __launch_bounds__(256) void ctx_f32(const float* __restrict__ enc,
                                               const float* __restrict__ alpha,
                                               float* __restrict__ ctx) {
    const int n = blockIdx.x;
    const int tid = threadIdx.x;
    float4 acc = {0.f, 0.f, 0.f, 0.f};
    for (int t = 0; t < T_DIM; ++t) {
        const float al = alpha[t * N_DIM + n];
        float4 ev = *reinterpret_cast<const float4*>(
            enc + (size_t)(t * N_DIM + n) * E_DIM + tid * 4);
        acc.x = fmaf(al, ev.x, acc.x);
        acc.y = fmaf(al, ev.y, acc.y);
        acc.z = fmaf(al, ev.z, acc.z);
        acc.w = fmaf(al, ev.w, acc.w);
    }
    *reinterpret_cast<float4*>(ctx + (size_t)n * E_DIM + tid * 4) = acc;
}

__global__ __launch_bounds__(256) void ctx_reduce_kernel(
    const float* __restrict__ partial, float* __restrict__ ctx, int nchunk) {
    const int idx = blockIdx.x * 256 + threadIdx.x;
    float s = 0.f;
    for (int c = 0; c < nchunk; ++c) s += partial[(size_t)c * 65536 + idx];
    ctx[idx] = s;
}

extern "C" void kernel_launch(void* const* d_in, const int* in_sizes, int n_in,
                              void* d_out, int out_size, void* d_ws,
                              size_t ws_size, hipStream_t stream) {
    const float* enc = (const float*)d_in[0];    // [T,N,E]
    const float* dec_h = (const float*)d_in[1];  // [N,D]
    const float* W_e = (const float*)d_in[2];    // [A,E]
    const float* W_d = (const float*)d_in[3];    // [A,D]
    const float* v = (const float*)d_in[4];      // [1,A]

    float* out = (float*)d_out;
    float* ctx = out;            // 64*1024
    float* alpha = out + 65536;  // 2048*64

    float* ws = (float*)d_ws;
    float* d_proj = ws;                    // 16384 f
    float* scores = ws + 16384;            // 131072 f
    __bf16* Wp = (__bf16*)(ws + 147456);   // 131072 f worth
    float* partial = ws + 278528;          // 16*65536 f
    __bf16* enc_bf = (__bf16*)(ws + 278528 + 16 * 65536);  // 67108864 f worth

    const size_t need =
        (size_t)(278528 + 16 * 65536 + (size_t)T_DIM * N_DIM * E_DIM / 2) *
        sizeof(float);
    const bool big = ws_size >= need;

    convert_W<<<128, 256, 0, stream>>>(W_e, Wp);
    dproj_kernel<<<N_DIM, 256, 0, stream>>>(dec_h, W_d, d_proj);
    scores_mfma<<<(T_DIM * N_DIM) / 64, 256, 0, stream>>>(
        enc, Wp, d_proj, v, scores, big ? enc_bf : nullptr);
    softmax_kernel<<<N_DIM, 256, 0, stream>>>(scores, alpha);

    if (big) {
        dim3 g(N_DIM, 16);
        ctx_partial_bf<<<g, 256, 0, stream>>>(enc_bf, alpha, partial,
                                              T_DIM / 16, 16);
        ctx_reduce_kernel<<<256, 256, 0, stream>>>(partial, ctx, 16);
    } else {
        ctx_f32<<<N_DIM, 256, 0, stream>>>(enc, alpha, ctx);
    }
}

// Round 5
// 264.043 us; speedup vs baseline: 1.3539x; 1.3539x over previous
//
#include <hip/hip_runtime.h>
#include <math.h>

#define T_DIM 2048
#define N_DIM 64
#define E_DIM 1024
#define A_DIM 256
#define TCHUNK 32
#define NCHUNK (T_DIM / TCHUNK)  // 64

typedef __bf16 bf16x8 __attribute__((ext_vector_type(8)));
typedef __bf16 bf16x4 __attribute__((ext_vector_type(4)));
typedef float f32x4 __attribute__((ext_vector_type(4)));

__device__ __forceinline__ float tanh_fast(float x) {
    float xc = fminf(fmaxf(x, -15.f), 15.f);
    float e = __expf(2.f * xc);
    return (e - 1.f) / (e + 1.f);
}

// ---- W_e fp32 [A,E] -> bf16 permuted: unit (ks,g,a) = W_e[a][ks*32+g*8..+8]
// at unit offset (ks*4+g)*256 + a   (ks 0..31, g 0..3, a 0..255)
__global__ __launch_bounds__(256) void convert_W(const float* __restrict__ W_e,
                                                 __bf16* __restrict__ Wp) {
    const int uid = blockIdx.x * 256 + threadIdx.x;
    const int a = uid >> 7;
    const int c = uid & 127;
    const float4* src = (const float4*)(W_e + (size_t)a * E_DIM + c * 8);
    float4 x0 = src[0], x1 = src[1];
    bf16x8 o;
    o[0] = (__bf16)x0.x; o[1] = (__bf16)x0.y; o[2] = (__bf16)x0.z; o[3] = (__bf16)x0.w;
    o[4] = (__bf16)x1.x; o[5] = (__bf16)x1.y; o[6] = (__bf16)x1.z; o[7] = (__bf16)x1.w;
    *(bf16x8*)(Wp + ((size_t)c * 256 + a) * 8) = o;
}

// ---------------- d_proj[n][a] = dot(dec_h[n,:], W_d[a,:]) ----------------
__global__ __launch_bounds__(256) void dproj_kernel(
    const float* __restrict__ dec_h, const float* __restrict__ W_d,
    float* __restrict__ d_proj) {
    __shared__ float dec[E_DIM];
    const int n = blockIdx.x;
    const int tid = threadIdx.x;
    reinterpret_cast<float4*>(dec)[tid] =
        reinterpret_cast<const float4*>(dec_h + (size_t)n * E_DIM)[tid];
    __syncthreads();
    const float* w = W_d + (size_t)tid * E_DIM;
    float acc = 0.f;
#pragma unroll 4
    for (int e = 0; e < E_DIM; e += 4) {
        float4 wv = *reinterpret_cast<const float4*>(w + e);
        acc = fmaf(wv.x, dec[e], acc);
        acc = fmaf(wv.y, dec[e + 1], acc);
        acc = fmaf(wv.z, dec[e + 2], acc);
        acc = fmaf(wv.w, dec[e + 3], acc);
    }
    d_proj[n * A_DIM + tid] = acc;
}

// ---- flash kernel: block = (n, 32-t chunk). enc read ONCE.
// GEMM 32x256xK=1024 (bf16 MFMA, persistent LDS A-tile), scores -> local
// (m,Z,weights) -> weighted row-sum from LDS -> partial ctx.
__global__ __launch_bounds__(256, 2) void flash_kernel(
    const float* __restrict__ enc, const __bf16* __restrict__ Wp,
    const float* __restrict__ dproj, const float* __restrict__ v,
    float* __restrict__ scores, float* __restrict__ partial,
    float* __restrict__ ms, float* __restrict__ zs) {
    __shared__ __align__(16) __bf16 Atile[TCHUNK * E_DIM];  // 64 KB, persistent
    // tail 640 B of Atile double as red[128] + wls[32] (units 4056..4095);
    // only written after the final MFMA barrier.
    float* red = ((float*)Atile) + 16384 - 160;  // 128 floats
    float* wls = red + 128;                      // 32 floats

    const int tid = threadIdx.x;
    const int bid = blockIdx.x;
    const int n = bid & (N_DIM - 1);
    const int c = bid >> 6;
    const int t0 = c * TCHUNK;
    const int wn = tid >> 6, lane = tid & 63;
    const int lr = lane & 15, lg = lane >> 4;

    f32x4 acc[2][4];
#pragma unroll
    for (int i = 0; i < 2; ++i)
#pragma unroll
        for (int j = 0; j < 4; ++j) acc[i][j] = (f32x4){0.f, 0.f, 0.f, 0.f};

    // per-lane v and dproj terms (n fixed for whole block)
    float vv[4], dp[4];
#pragma unroll
    for (int fn = 0; fn < 4; ++fn) {
        const int a = wn * 64 + fn * 16 + lr;
        vv[fn] = v[a];
        dp[fn] = dproj[n * A_DIM + a];
    }

    // staging: thread -> (row, 8-float group); one iter covers K=64 (2 subtiles)
    const int srow = tid >> 3, sg8 = tid & 7;
    const int sg = sg8 >> 1, shalf = sg8 & 1;
    const float* encRow =
        enc + ((size_t)(t0 + srow) * N_DIM + n) * E_DIM + sg8 * 4;
    const bf16x8* WpV = (const bf16x8*)Wp;

    // prologue: load kt=0 (cols 0..63)
    float4 c0a = *(const float4*)(encRow);
    float4 c0b = *(const float4*)(encRow + 32);

    for (int kt = 0; kt < 16; ++kt) {
        // B fragments for this K=64 step (L2-resident Wp)
        bf16x8 bfr[8];
        const int ks0 = kt * 2;
#pragma unroll
        for (int s = 0; s < 2; ++s)
#pragma unroll
            for (int fn = 0; fn < 4; ++fn)
                bfr[s * 4 + fn] = WpV[(size_t)(ks0 + s) * 1024 + lg * 256 +
                                      wn * 64 + fn * 16 + lr];
        // prefetch next A chunk
        float4 na, nb;
        if (kt < 15) {
            const float* p = encRow + (kt + 1) * 64;
            na = *(const float4*)p;
            nb = *(const float4*)(p + 32);
        }
        // cvt + write current A chunk into persistent slots ks0, ks0+1
        {
            bf16x4 w0, w1;
            w0[0] = (__bf16)c0a.x; w0[1] = (__bf16)c0a.y;
            w0[2] = (__bf16)c0a.z; w0[3] = (__bf16)c0a.w;
            w1[0] = (__bf16)c0b.x; w1[1] = (__bf16)c0b.y;
            w1[2] = (__bf16)c0b.z; w1[3] = (__bf16)c0b.w;
            const int u0 = ks0 * 128 + sg * 32 + (srow ^ ((ks0 * 4 + sg) & 7));
            const int u1 = (ks0 + 1) * 128 + sg * 32 +
                           (srow ^ (((ks0 + 1) * 4 + sg) & 7));
            *(bf16x4*)((char*)Atile + u0 * 16 + shalf * 8) = w0;
            *(bf16x4*)((char*)Atile + u1 * 16 + shalf * 8) = w1;
        }
        __syncthreads();  // slots ks0,ks0+1 visible (drains prefetch too)
#pragma unroll
        for (int s = 0; s < 2; ++s) {
            const int ks = ks0 + s;
#pragma unroll
            for (int fm = 0; fm < 2; ++fm) {
                const int row = fm * 16 + lr;
                const int u =
                    ks * 128 + lg * 32 + (row ^ ((ks * 4 + lg) & 7));
                bf16x8 af = *(const bf16x8*)((const char*)Atile + u * 16);
                acc[fm][0] = __builtin_amdgcn_mfma_f32_16x16x32_bf16(af, bfr[s*4+0], acc[fm][0], 0, 0, 0);
                acc[fm][1] = __builtin_amdgcn_mfma_f32_16x16x32_bf16(af, bfr[s*4+1], acc[fm][1], 0, 0, 0);
                acc[fm][2] = __builtin_amdgcn_mfma_f32_16x16x32_bf16(af, bfr[s*4+2], acc[fm][2], 0, 0, 0);
                acc[fm][3] = __builtin_amdgcn_mfma_f32_16x16x32_bf16(af, bfr[s*4+3], acc[fm][3], 0, 0, 0);
            }
        }
        c0a = na;
        c0b = nb;
    }

    // ---- scores epilogue: tanh(e+d) dot v, reduce over a ----
    float pr[2][4];
#pragma unroll
    for (int fm = 0; fm < 2; ++fm) {
#pragma unroll
        for (int reg = 0; reg < 4; ++reg) {
            float p = 0.f;
#pragma unroll
            for (int fn = 0; fn < 4; ++fn)
                p = fmaf(vv[fn], tanh_fast(acc[fm][fn][reg] + dp[fn]), p);
            p += __shfl_xor(p, 1);
            p += __shfl_xor(p, 2);
            p += __shfl_xor(p, 4);
            p += __shfl_xor(p, 8);
            pr[fm][reg] = p;
        }
    }
    __syncthreads();  // all MFMA LDS reads done -> tail overlay now safe
    if (lr == 0) {
#pragma unroll
        for (int fm = 0; fm < 2; ++fm)
#pragma unroll
            for (int reg = 0; reg < 4; ++reg)
                red[wn * 32 + fm * 16 + lg * 4 + reg] = pr[fm][reg];
    }
    __syncthreads();
    if (tid < TCHUNK) {
        float s = red[tid] + red[32 + tid] + red[64 + tid] + red[96 + tid];
        scores[(t0 + tid) * N_DIM + n] = s;
        if (partial) {
            float m = s;
            m = fmaxf(m, __shfl_xor(m, 1));
            m = fmaxf(m, __shfl_xor(m, 2));
            m = fmaxf(m, __shfl_xor(m, 4));
            m = fmaxf(m, __shfl_xor(m, 8));
            m = fmaxf(m, __shfl_xor(m, 16));
            float w = __expf(s - m);
            float Z = w;
            Z += __shfl_xor(Z, 1);
            Z += __shfl_xor(Z, 2);
            Z += __shfl_xor(Z, 4);
            Z += __shfl_xor(Z, 8);
            Z += __shfl_xor(Z, 16);
            wls[tid] = w;
            if (tid == 0) {
                ms[n * NCHUNK + c] = m;
                zs[n * NCHUNK + c] = Z;
            }
        }
    }
    __syncthreads();

    if (!partial) return;
    // ---- weighted row-sum from LDS (bf16) -> ctx partial ----
    f32x4 a4 = (f32x4){0.f, 0.f, 0.f, 0.f};
    if (tid < 252) {
        const int ks = tid >> 3, g = (tid >> 1) & 3, half = tid & 1;
        const int q = (ks * 4 + g) & 7;
        const int ubase = ks * 128 + g * 32;
#pragma unroll 4
        for (int r = 0; r < TCHUNK; ++r) {
            const float w = wls[r];
            bf16x4 ev = *(const bf16x4*)((const char*)Atile +
                                         (ubase + (r ^ q)) * 16 + half * 8);
            a4[0] = fmaf(w, (float)ev[0], a4[0]);
            a4[1] = fmaf(w, (float)ev[1], a4[1]);
            a4[2] = fmaf(w, (float)ev[2], a4[2]);
            a4[3] = fmaf(w, (float)ev[3], a4[3]);
        }
    } else {  // columns living under the red/wls overlay: read from L2
#pragma unroll 4
        for (int r = 0; r < TCHUNK; ++r) {
            const float w = wls[r];
            float4 ev = *(const float4*)(
                enc + ((size_t)(t0 + r) * N_DIM + n) * E_DIM + tid * 4);
            a4[0] = fmaf(w, ev.x, a4[0]);
            a4[1] = fmaf(w, ev.y, a4[1]);
            a4[2] = fmaf(w, ev.z, a4[2]);
            a4[3] = fmaf(w, ev.w, a4[3]);
        }
    }
    *(f32x4*)(partial + ((size_t)c * N_DIM + n) * E_DIM + tid * 4) = a4;
}

// ---- combine: per n, flash rescale of 64 chunk partials + alpha ----
__global__ __launch_bounds__(256) void combine_kernel(
    const float* __restrict__ partial, const float* __restrict__ ms,
    const float* __restrict__ zs, const float* __restrict__ scores,
    float* __restrict__ ctx, float* __restrict__ alpha) {
    __shared__ float scale[NCHUNK];
    __shared__ float MZ[2];
    const int n = blockIdx.x;
    const int tid = threadIdx.x;
    if (tid < NCHUNK) {
        float m = ms[n * NCHUNK + tid];
        float M = m;
        M = fmaxf(M, __shfl_xor(M, 1));
        M = fmaxf(M, __shfl_xor(M, 2));
        M = fmaxf(M, __shfl_xor(M, 4));
        M = fmaxf(M, __shfl_xor(M, 8));
        M = fmaxf(M, __shfl_xor(M, 16));
        M = fmaxf(M, __shfl_xor(M, 32));
        float e = __expf(m - M);
        float z = zs[n * NCHUNK + tid] * e;
        float Z = z;
        Z += __shfl_xor(Z, 1);
        Z += __shfl_xor(Z, 2);
        Z += __shfl_xor(Z, 4);
        Z += __shfl_xor(Z, 8);
        Z += __shfl_xor(Z, 16);
        Z += __shfl_xor(Z, 32);
        scale[tid] = e;
        if (tid == 0) {
            MZ[0] = M;
            MZ[1] = Z;
        }
    }
    __syncthreads();
    const float M = MZ[0];
    const float invZ = 1.f / MZ[1];
    f32x4 a4 = (f32x4){0.f, 0.f, 0.f, 0.f};
    for (int c = 0; c < NCHUNK; ++c) {
        const float s = scale[c] * invZ;
        float4 p = *(const float4*)(partial +
                                    ((size_t)c * N_DIM + n) * E_DIM + tid * 4);
        a4[0] = fmaf(s, p.x, a4[0]);
        a4[1] = fmaf(s, p.y, a4[1]);
        a4[2] = fmaf(s, p.z, a4[2]);
        a4[3] = fmaf(s, p.w, a4[3]);
    }
    *(f32x4*)(ctx + (size_t)n * E_DIM + tid * 4) = a4;
    for (int t = tid; t < T_DIM; t += 256)
        alpha[t * N_DIM + n] = __expf(scores[t * N_DIM + n] - M) * invZ;
}

// ---------------- fallback path (small ws): softmax + fp32 ctx ------------
__global__ __launch_bounds__(256) void softmax_kernel(
    const float* __restrict__ scores, float* __restrict__ alpha) {
    __shared__ float red[256];
    const int n = blockIdx.x;
    const int tid = threadIdx.x;
    float m = -3.4e38f;
    for (int t = tid; t < T_DIM; t += 256)
        m = fmaxf(m, scores[t * N_DIM + n]);
    red[tid] = m;
    __syncthreads();
    for (int s = 128; s; s >>= 1) {
        if (tid < s) red[tid] = fmaxf(red[tid], red[tid + s]);
        __syncthreads();
    }
    m = red[0];
    __syncthreads();
    float sum = 0.f;
    for (int t = tid; t < T_DIM; t += 256)
        sum += expf(scores[t * N_DIM + n] - m);
    red[tid] = sum;
    __syncthreads();
    for (int s = 128; s; s >>= 1) {
        if (tid < s) red[tid] += red[tid + s];
        __syncthreads();
    }
    const float inv = 1.f / red[0];
    for (int t = tid; t < T_DIM; t += 256)
        alpha[t * N_DIM + n] = expf(scores[t * N_DIM + n] - m) * inv;
}

__global__ __launch_bounds__(256) void ctx_f32(const float* __restrict__ enc,
                                               const float* __restrict__ alpha,
                                               float* __restrict__ ctx) {
    const int n = blockIdx.x;
    const int tid = threadIdx.x;
    float4 acc = {0.f, 0.f, 0.f, 0.f};
    for (int t = 0; t < T_DIM; ++t) {
        const float al = alpha[t * N_DIM + n];
        float4 ev = *reinterpret_cast<const float4*>(
            enc + (size_t)(t * N_DIM + n) * E_DIM + tid * 4);
        acc.x = fmaf(al, ev.x, acc.x);
        acc.y = fmaf(al, ev.y, acc.y);
        acc.z = fmaf(al, ev.z, acc.z);
        acc.w = fmaf(al, ev.w, acc.w);
    }
    *reinterpret_cast<float4*>(ctx + (size_t)n * E_DIM + tid * 4) = acc;
}

extern "C" void kernel_launch(void* const* d_in, const int* in_sizes, int n_in,
                              void* d_out, int out_size, void* d_ws,
                              size_t ws_size, hipStream_t stream) {
    const float* enc = (const float*)d_in[0];    // [T,N,E]
    const float* dec_h = (const float*)d_in[1];  // [N,D]
    const float* W_e = (const float*)d_in[2];    // [A,E]
    const float* W_d = (const float*)d_in[3];    // [A,D]
    const float* v = (const float*)d_in[4];      // [1,A]

    float* out = (float*)d_out;
    float* ctx = out;            // 64*1024
    float* alpha = out + 65536;  // 2048*64

    float* ws = (float*)d_ws;
    float* d_proj = ws;                   // 16384 f
    float* scores = ws + 16384;           // 131072 f
    __bf16* Wp = (__bf16*)(ws + 147456);  // 131072 f worth
    float* ms = ws + 278528;              // 4096 f
    float* zs = ws + 282624;              // 4096 f
    float* partial = ws + 286720;         // 64*64*1024 = 4194304 f

    const size_t need = (size_t)(286720 + NCHUNK * N_DIM * E_DIM) * sizeof(float);
    const bool big = ws_size >= need;

    convert_W<<<128, 256, 0, stream>>>(W_e, Wp);
    dproj_kernel<<<N_DIM, 256, 0, stream>>>(dec_h, W_d, d_proj);
    flash_kernel<<<T_DIM / TCHUNK * N_DIM, 256, 0, stream>>>(
        enc, Wp, d_proj, v, scores, big ? partial : nullptr, ms, zs);
    if (big) {
        combine_kernel<<<N_DIM, 256, 0, stream>>>(partial, ms, zs, scores,
                                                  ctx, alpha);
    } else {
        softmax_kernel<<<N_DIM, 256, 0, stream>>>(scores, alpha);
        ctx_f32<<<N_DIM, 256, 0, stream>>>(enc, alpha, ctx);
    }
}

// Round 6
// 232.933 us; speedup vs baseline: 1.5347x; 1.1336x over previous
//
#include <hip/hip_runtime.h>
#include <math.h>

#define T_DIM 2048
#define N_DIM 64
#define E_DIM 1024
#define A_DIM 256
#define TCHUNK 32
#define NCHUNK (T_DIM / TCHUNK)  // 64

typedef __bf16 bf16x8 __attribute__((ext_vector_type(8)));
typedef __bf16 bf16x4 __attribute__((ext_vector_type(4)));
typedef float f32x4 __attribute__((ext_vector_type(4)));

__device__ __forceinline__ float tanh_fast(float x) {
    float xc = fminf(fmaxf(x, -15.f), 15.f);
    float e = __expf(2.f * xc);
    return (e - 1.f) / (e + 1.f);
}

// ---- W_e fp32 [A,E] -> bf16 permuted: unit (ks,g,a) = W_e[a][ks*32+g*8..+8]
// at unit offset (ks*4+g)*256 + a
__global__ __launch_bounds__(256) void convert_W(const float* __restrict__ W_e,
                                                 __bf16* __restrict__ Wp) {
    const int uid = blockIdx.x * 256 + threadIdx.x;
    const int a = uid >> 7;
    const int c = uid & 127;
    const float4* src = (const float4*)(W_e + (size_t)a * E_DIM + c * 8);
    float4 x0 = src[0], x1 = src[1];
    bf16x8 o;
    o[0] = (__bf16)x0.x; o[1] = (__bf16)x0.y; o[2] = (__bf16)x0.z; o[3] = (__bf16)x0.w;
    o[4] = (__bf16)x1.x; o[5] = (__bf16)x1.y; o[6] = (__bf16)x1.z; o[7] = (__bf16)x1.w;
    *(bf16x8*)(Wp + ((size_t)c * 256 + a) * 8) = o;
}

// ---------------- d_proj[n][a] = dot(dec_h[n,:], W_d[a,:]) ----------------
__global__ __launch_bounds__(256) void dproj_kernel(
    const float* __restrict__ dec_h, const float* __restrict__ W_d,
    float* __restrict__ d_proj) {
    __shared__ float dec[E_DIM];
    const int n = blockIdx.x;
    const int tid = threadIdx.x;
    reinterpret_cast<float4*>(dec)[tid] =
        reinterpret_cast<const float4*>(dec_h + (size_t)n * E_DIM)[tid];
    __syncthreads();
    const float* w = W_d + (size_t)tid * E_DIM;
    float acc = 0.f;
#pragma unroll 4
    for (int e = 0; e < E_DIM; e += 4) {
        float4 wv = *reinterpret_cast<const float4*>(w + e);
        acc = fmaf(wv.x, dec[e], acc);
        acc = fmaf(wv.y, dec[e + 1], acc);
        acc = fmaf(wv.z, dec[e + 2], acc);
        acc = fmaf(wv.w, dec[e + 3], acc);
    }
    d_proj[n * A_DIM + tid] = acc;
}

// ---- flash: block=(n, 32-t chunk), 512 thr = 8 waves (32 a-cols each).
// K=128 per barrier (8 barriers). Persistent 64KB bf16 A-tile; enc read ONCE.
__global__ __launch_bounds__(512, 4) void flash_kernel(
    const float* __restrict__ enc, const __bf16* __restrict__ Wp,
    const float* __restrict__ dproj, const float* __restrict__ v,
    float* __restrict__ scores, float* __restrict__ partial,
    float* __restrict__ ms, float* __restrict__ zs) {
    __shared__ __align__(16) __bf16 Atile[TCHUNK * E_DIM];  // 64 KB persistent
    // tail 1152 B (units 4024..4095) double as red[256]+wls[32]; written only
    // after the post-MFMA barrier.
    float* red = ((float*)Atile) + 16384 - 288;
    float* wls = red + 256;

    const int tid = threadIdx.x;
    const int bid = blockIdx.x;
    const int n = bid & (N_DIM - 1);
    const int c = bid >> 6;
    const int t0 = c * TCHUNK;
    const int wn = tid >> 6;  // wave 0..7 -> a-cols wn*32..+32
    const int lane = tid & 63;
    const int lr = lane & 15, lg = lane >> 4;

    f32x4 acc[2][2];
#pragma unroll
    for (int i = 0; i < 2; ++i)
#pragma unroll
        for (int j = 0; j < 2; ++j) acc[i][j] = (f32x4){0.f, 0.f, 0.f, 0.f};

    float vv[2], dp[2];
#pragma unroll
    for (int fn = 0; fn < 2; ++fn) {
        const int a = wn * 32 + fn * 16 + lr;
        vv[fn] = v[a];
        dp[fn] = dproj[n * A_DIM + a];
    }

    // staging map: 512 threads -> (row 0..31, sg 0..15); per iter a thread
    // loads cols it*128+sg*4 and it*128+64+sg*4 of its row.
    const int srow = tid >> 4, sg = tid & 15;
    const int sgg = (sg & 7) >> 1, sbh = sg & 1;  // 8-col group, 8B half
    const int sks = sg >> 3;                      // 0/1 -> ks offset
    const float* encRow =
        enc + ((size_t)(t0 + srow) * N_DIM + n) * E_DIM + sg * 4;
    const bf16x8* WpV = (const bf16x8*)Wp;

    float4 c0a = *(const float4*)encRow;
    float4 c0b = *(const float4*)(encRow + 64);

#pragma unroll 1
    for (int it = 0; it < 8; ++it) {
        // cvt + write current K=128 chunk into slots it*4..it*4+3 (write-once)
        {
            const int ks1 = it * 4 + sks, ks2 = ks1 + 2;
            bf16x4 w0, w1;
            w0[0] = (__bf16)c0a.x; w0[1] = (__bf16)c0a.y;
            w0[2] = (__bf16)c0a.z; w0[3] = (__bf16)c0a.w;
            w1[0] = (__bf16)c0b.x; w1[1] = (__bf16)c0b.y;
            w1[2] = (__bf16)c0b.z; w1[3] = (__bf16)c0b.w;
            const int u1 = ks1 * 128 + sgg * 32 + (srow ^ ((ks1 * 4 + sgg) & 7));
            const int u2 = ks2 * 128 + sgg * 32 + (srow ^ ((ks2 * 4 + sgg) & 7));
            *(bf16x4*)((char*)Atile + u1 * 16 + sbh * 8) = w0;
            *(bf16x4*)((char*)Atile + u2 * 16 + sbh * 8) = w1;
        }
        // B fragments for this K-step (L2-resident Wp)
        bf16x8 bfr[4][2];
#pragma unroll
        for (int s = 0; s < 4; ++s)
#pragma unroll
            for (int fn = 0; fn < 2; ++fn)
                bfr[s][fn] = WpV[(size_t)(it * 4 + s) * 1024 + lg * 256 +
                                 wn * 32 + fn * 16 + lr];
        // prefetch next K=128 chunk (HBM)
        float4 na, nb;
        if (it < 7) {
            const float* p = encRow + (it + 1) * 128;
            na = *(const float4*)p;
            nb = *(const float4*)(p + 64);
        }
        __syncthreads();  // slots it*4..+3 visible
#pragma unroll
        for (int s = 0; s < 4; ++s) {
            const int ks = it * 4 + s;
#pragma unroll
            for (int fm = 0; fm < 2; ++fm) {
                const int u =
                    ks * 128 + lg * 32 + ((fm * 16 + lr) ^ ((ks * 4 + lg) & 7));
                bf16x8 af = *(const bf16x8*)((const char*)Atile + u * 16);
                acc[fm][0] = __builtin_amdgcn_mfma_f32_16x16x32_bf16(
                    af, bfr[s][0], acc[fm][0], 0, 0, 0);
                acc[fm][1] = __builtin_amdgcn_mfma_f32_16x16x32_bf16(
                    af, bfr[s][1], acc[fm][1], 0, 0, 0);
            }
        }
        c0a = na;
        c0b = nb;
    }

    // ---- scores epilogue ----
    float pr[2][4];
#pragma unroll
    for (int fm = 0; fm < 2; ++fm) {
#pragma unroll
        for (int reg = 0; reg < 4; ++reg) {
            float p = fmaf(vv[0], tanh_fast(acc[fm][0][reg] + dp[0]), 0.f);
            p = fmaf(vv[1], tanh_fast(acc[fm][1][reg] + dp[1]), p);
            p += __shfl_xor(p, 1);
            p += __shfl_xor(p, 2);
            p += __shfl_xor(p, 4);
            p += __shfl_xor(p, 8);
            pr[fm][reg] = p;
        }
    }
    __syncthreads();  // all MFMA LDS reads done -> overlay safe
    if (lr == 0) {
#pragma unroll
        for (int fm = 0; fm < 2; ++fm)
#pragma unroll
            for (int reg = 0; reg < 4; ++reg)
                red[wn * 32 + fm * 16 + lg * 4 + reg] = pr[fm][reg];
    }
    __syncthreads();
    if (tid < TCHUNK) {
        float s = 0.f;
#pragma unroll
        for (int w = 0; w < 8; ++w) s += red[w * 32 + tid];
        scores[(t0 + tid) * N_DIM + n] = s;
        if (partial) {
            float m = s;
            m = fmaxf(m, __shfl_xor(m, 1));
            m = fmaxf(m, __shfl_xor(m, 2));
            m = fmaxf(m, __shfl_xor(m, 4));
            m = fmaxf(m, __shfl_xor(m, 8));
            m = fmaxf(m, __shfl_xor(m, 16));
            float w = __expf(s - m);
            float Z = w;
            Z += __shfl_xor(Z, 1);
            Z += __shfl_xor(Z, 2);
            Z += __shfl_xor(Z, 4);
            Z += __shfl_xor(Z, 8);
            Z += __shfl_xor(Z, 16);
            wls[tid] = w;
            if (tid == 0) {
                ms[n * NCHUNK + c] = m;
                zs[n * NCHUNK + c] = Z;
            }
        }
    }
    __syncthreads();

    if (!partial) return;
    // ---- weighted row-sum from LDS tile -> ctx partial ----
    // colslot cs = ks*8 + g*2 + bhalf (4 cols each); thread pair splits rows.
    const int cs = tid >> 1, rh = tid & 1;
    const int ks = cs >> 3, gg = (cs >> 1) & 3, bh = cs & 1;
    const int colbase = ks * 32 + gg * 8 + bh * 4;
    f32x4 a4 = (f32x4){0.f, 0.f, 0.f, 0.f};
    if (cs < 250) {  // slots under the red/wls overlay excluded
        const int q = (ks * 4 + gg) & 7;
        const int ubase = ks * 128 + gg * 32;
#pragma unroll 4
        for (int r = rh * 16; r < rh * 16 + 16; ++r) {
            const float w = wls[r];
            bf16x4 ev = *(const bf16x4*)((const char*)Atile +
                                         (ubase + (r ^ q)) * 16 + bh * 8);
            a4[0] = fmaf(w, (float)ev[0], a4[0]);
            a4[1] = fmaf(w, (float)ev[1], a4[1]);
            a4[2] = fmaf(w, (float)ev[2], a4[2]);
            a4[3] = fmaf(w, (float)ev[3], a4[3]);
        }
    } else {  // overlay region: re-read those columns from cache/HBM
#pragma unroll 4
        for (int r = rh * 16; r < rh * 16 + 16; ++r) {
            const float w = wls[r];
            float4 ev = *(const float4*)(
                enc + ((size_t)(t0 + r) * N_DIM + n) * E_DIM + colbase);
            a4[0] = fmaf(w, ev.x, a4[0]);
            a4[1] = fmaf(w, ev.y, a4[1]);
            a4[2] = fmaf(w, ev.z, a4[2]);
            a4[3] = fmaf(w, ev.w, a4[3]);
        }
    }
#pragma unroll
    for (int k = 0; k < 4; ++k) a4[k] += __shfl_xor(a4[k], 1);
    if (rh == 0)
        *(f32x4*)(partial + ((size_t)c * N_DIM + n) * E_DIM + colbase) = a4;
}

// ---- combine: per n, flash rescale of 64 chunk partials + alpha ----
__global__ __launch_bounds__(256) void combine_kernel(
    const float* __restrict__ partial, const float* __restrict__ ms,
    const float* __restrict__ zs, const float* __restrict__ scores,
    float* __restrict__ ctx, float* __restrict__ alpha) {
    __shared__ float scale[NCHUNK];
    __shared__ float MZ[2];
    const int n = blockIdx.x;
    const int tid = threadIdx.x;
    if (tid < NCHUNK) {
        float m = ms[n * NCHUNK + tid];
        float M = m;
        M = fmaxf(M, __shfl_xor(M, 1));
        M = fmaxf(M, __shfl_xor(M, 2));
        M = fmaxf(M, __shfl_xor(M, 4));
        M = fmaxf(M, __shfl_xor(M, 8));
        M = fmaxf(M, __shfl_xor(M, 16));
        M = fmaxf(M, __shfl_xor(M, 32));
        float e = __expf(m - M);
        float z = zs[n * NCHUNK + tid] * e;
        float Z = z;
        Z += __shfl_xor(Z, 1);
        Z += __shfl_xor(Z, 2);
        Z += __shfl_xor(Z, 4);
        Z += __shfl_xor(Z, 8);
        Z += __shfl_xor(Z, 16);
        Z += __shfl_xor(Z, 32);
        scale[tid] = e;
        if (tid == 0) {
            MZ[0] = M;
            MZ[1] = Z;
        }
    }
    __syncthreads();
    const float M = MZ[0];
    const float invZ = 1.f / MZ[1];
    f32x4 a4 = (f32x4){0.f, 0.f, 0.f, 0.f};
#pragma unroll 4
    for (int c = 0; c < NCHUNK; ++c) {
        const float s = scale[c] * invZ;
        float4 p = *(const float4*)(partial +
                                    ((size_t)c * N_DIM + n) * E_DIM + tid * 4);
        a4[0] = fmaf(s, p.x, a4[0]);
        a4[1] = fmaf(s, p.y, a4[1]);
        a4[2] = fmaf(s, p.z, a4[2]);
        a4[3] = fmaf(s, p.w, a4[3]);
    }
    *(f32x4*)(ctx + (size_t)n * E_DIM + tid * 4) = a4;
    for (int t = tid; t < T_DIM; t += 256)
        alpha[t * N_DIM + n] = __expf(scores[t * N_DIM + n] - M) * invZ;
}

// ---------------- fallback path (small ws): softmax + fp32 ctx ------------
__global__ __launch_bounds__(256) void softmax_kernel(
    const float* __restrict__ scores, float* __restrict__ alpha) {
    __shared__ float red[256];
    const int n = blockIdx.x;
    const int tid = threadIdx.x;
    float m = -3.4e38f;
    for (int t = tid; t < T_DIM; t += 256)
        m = fmaxf(m, scores[t * N_DIM + n]);
    red[tid] = m;
    __syncthreads();
    for (int s = 128; s; s >>= 1) {
        if (tid < s) red[tid] = fmaxf(red[tid], red[tid + s]);
        __syncthreads();
    }
    m = red[0];
    __syncthreads();
    float sum = 0.f;
    for (int t = tid; t < T_DIM; t += 256)
        sum += expf(scores[t * N_DIM + n] - m);
    red[tid] = sum;
    __syncthreads();
    for (int s = 128; s; s >>= 1) {
        if (tid < s) red[tid] += red[tid + s];
        __syncthreads();
    }
    const float inv = 1.f / red[0];
    for (int t = tid; t < T_DIM; t += 256)
        alpha[t * N_DIM + n] = expf(scores[t * N_DIM + n] - m) * inv;
}

__global__ __launch_bounds__(256) void ctx_f32(const float* __restrict__ enc,
                                               const float* __restrict__ alpha,
                                               float* __restrict__ ctx) {
    const int n = blockIdx.x;
    const int tid = threadIdx.x;
    float4 acc = {0.f, 0.f, 0.f, 0.f};
    for (int t = 0; t < T_DIM; ++t) {
        const float al = alpha[t * N_DIM + n];
        float4 ev = *reinterpret_cast<const float4*>(
            enc + (size_t)(t * N_DIM + n) * E_DIM + tid * 4);
        acc.x = fmaf(al, ev.x, acc.x);
        acc.y = fmaf(al, ev.y, acc.y);
        acc.z = fmaf(al, ev.z, acc.z);
        acc.w = fmaf(al, ev.w, acc.w);
    }
    *reinterpret_cast<float4*>(ctx + (size_t)n * E_DIM + tid * 4) = acc;
}

extern "C" void kernel_launch(void* const* d_in, const int* in_sizes, int n_in,
                              void* d_out, int out_size, void* d_ws,
                              size_t ws_size, hipStream_t stream) {
    const float* enc = (const float*)d_in[0];    // [T,N,E]
    const float* dec_h = (const float*)d_in[1];  // [N,D]
    const float* W_e = (const float*)d_in[2];    // [A,E]
    const float* W_d = (const float*)d_in[3];    // [A,D]
    const float* v = (const float*)d_in[4];      // [1,A]

    float* out = (float*)d_out;
    float* ctx = out;            // 64*1024
    float* alpha = out + 65536;  // 2048*64

    float* ws = (float*)d_ws;
    float* d_proj = ws;                   // 16384 f
    float* scores = ws + 16384;           // 131072 f
    __bf16* Wp = (__bf16*)(ws + 147456);  // 131072 f worth
    float* ms = ws + 278528;              // 4096 f
    float* zs = ws + 282624;              // 4096 f
    float* partial = ws + 286720;         // 64*64*1024 = 4194304 f

    const size_t need =
        (size_t)(286720 + NCHUNK * N_DIM * E_DIM) * sizeof(float);
    const bool big = ws_size >= need;

    convert_W<<<128, 256, 0, stream>>>(W_e, Wp);
    dproj_kernel<<<N_DIM, 256, 0, stream>>>(dec_h, W_d, d_proj);
    flash_kernel<<<T_DIM / TCHUNK * N_DIM, 512, 0, stream>>>(
        enc, Wp, d_proj, v, scores, big ? partial : nullptr, ms, zs);
    if (big) {
        combine_kernel<<<N_DIM, 256, 0, stream>>>(partial, ms, zs, scores,
                                                  ctx, alpha);
    } else {
        softmax_kernel<<<N_DIM, 256, 0, stream>>>(scores, alpha);
        ctx_f32<<<N_DIM, 256, 0, stream>>>(enc, alpha, ctx);
    }
}

// Round 7
// 228.434 us; speedup vs baseline: 1.5649x; 1.0197x over previous
//
#include <hip/hip_runtime.h>
#include <math.h>

#define T_DIM 2048
#define N_DIM 64
#define E_DIM 1024
#define A_DIM 256
#define TCHUNK 32
#define NCHUNK (T_DIM / TCHUNK)  // 64

typedef __bf16 bf16x8 __attribute__((ext_vector_type(8)));
typedef __bf16 bf16x4 __attribute__((ext_vector_type(4)));
typedef float f32x4 __attribute__((ext_vector_type(4)));

__device__ __forceinline__ float tanh_fast(float x) {
    float xc = fminf(fmaxf(x, -15.f), 15.f);
    float e = __expf(2.f * xc);
    return (e - 1.f) / (e + 1.f);
}

// LDS-write-ordering barrier that does NOT drain outstanding global loads
// (compiler's __syncthreads inserts s_waitcnt vmcnt(0); we only need lgkm).
__device__ __forceinline__ void lds_barrier() {
    asm volatile("s_waitcnt lgkmcnt(0)\n\ts_barrier" ::: "memory");
}

// ---- fused prep: blocks 0..127 convert W_e -> bf16 permuted Wp;
//      blocks 128..191 compute d_proj[n][a].
__global__ __launch_bounds__(256) void prep_kernel(
    const float* __restrict__ W_e, const float* __restrict__ dec_h,
    const float* __restrict__ W_d, __bf16* __restrict__ Wp,
    float* __restrict__ d_proj) {
    __shared__ float dec[E_DIM];
    const int tid = threadIdx.x;
    if (blockIdx.x < 128) {
        const int uid = blockIdx.x * 256 + tid;
        const int a = uid >> 7;
        const int c = uid & 127;
        const float4* src = (const float4*)(W_e + (size_t)a * E_DIM + c * 8);
        float4 x0 = src[0], x1 = src[1];
        bf16x8 o;
        o[0] = (__bf16)x0.x; o[1] = (__bf16)x0.y; o[2] = (__bf16)x0.z; o[3] = (__bf16)x0.w;
        o[4] = (__bf16)x1.x; o[5] = (__bf16)x1.y; o[6] = (__bf16)x1.z; o[7] = (__bf16)x1.w;
        *(bf16x8*)(Wp + ((size_t)c * 256 + a) * 8) = o;
    } else {
        const int n = blockIdx.x - 128;
        reinterpret_cast<float4*>(dec)[tid] =
            reinterpret_cast<const float4*>(dec_h + (size_t)n * E_DIM)[tid];
        __syncthreads();
        const float* w = W_d + (size_t)tid * E_DIM;
        float acc = 0.f;
#pragma unroll 4
        for (int e = 0; e < E_DIM; e += 4) {
            float4 wv = *reinterpret_cast<const float4*>(w + e);
            acc = fmaf(wv.x, dec[e], acc);
            acc = fmaf(wv.y, dec[e + 1], acc);
            acc = fmaf(wv.z, dec[e + 2], acc);
            acc = fmaf(wv.w, dec[e + 3], acc);
        }
        d_proj[n * A_DIM + tid] = acc;
    }
}

// ---- flash: block=(n, 32-t chunk), 512 thr = 8 waves (32 a-cols each).
// K=128 per lgkm-barrier; 2-deep HBM prefetch kept in flight across barriers.
__global__ __launch_bounds__(512, 4) void flash_kernel(
    const float* __restrict__ enc, const __bf16* __restrict__ Wp,
    const float* __restrict__ dproj, const float* __restrict__ v,
    float* __restrict__ scores, float* __restrict__ partial,
    float* __restrict__ ms, float* __restrict__ zs) {
    __shared__ __align__(16) __bf16 Atile[TCHUNK * E_DIM];  // 64 KB persistent
    // tail 1152 B (units 4024..4095) double as red[256]+wls[32]; written only
    // after the post-MFMA __syncthreads.
    float* red = ((float*)Atile) + 16384 - 288;
    float* wls = red + 256;

    const int tid = threadIdx.x;
    const int bid = blockIdx.x;
    const int n = bid & (N_DIM - 1);
    const int c = bid >> 6;
    const int t0 = c * TCHUNK;
    const int wn = tid >> 6;  // wave 0..7 -> a-cols wn*32..+32
    const int lane = tid & 63;
    const int lr = lane & 15, lg = lane >> 4;

    f32x4 acc[2][2];
#pragma unroll
    for (int i = 0; i < 2; ++i)
#pragma unroll
        for (int j = 0; j < 2; ++j) acc[i][j] = (f32x4){0.f, 0.f, 0.f, 0.f};

    float vv[2], dp[2];
#pragma unroll
    for (int fn = 0; fn < 2; ++fn) {
        const int a = wn * 32 + fn * 16 + lr;
        vv[fn] = v[a];
        dp[fn] = dproj[n * A_DIM + a];
    }

    // staging map: thread -> (row 0..31, sg 0..15); per iter loads cols
    // it*128+sg*4 and it*128+64+sg*4 of its row.
    const int srow = tid >> 4, sg = tid & 15;
    const int sgg = (sg & 7) >> 1, sbh = sg & 1;
    const int sks = sg >> 3;
    const float* encRow =
        enc + ((size_t)(t0 + srow) * N_DIM + n) * E_DIM + sg * 4;
    const bf16x8* WpV = (const bf16x8*)Wp;

    // 2-deep prefetch: pa/pb = chunk it, qa/qb = chunk it+1
    float4 pa = *(const float4*)encRow;
    float4 pb = *(const float4*)(encRow + 64);
    float4 qa = *(const float4*)(encRow + 128);
    float4 qb = *(const float4*)(encRow + 192);

#pragma unroll
    for (int it = 0; it < 8; ++it) {
        // B fragments for this K-step (L2-resident Wp) — issued first
        bf16x8 bfr[4][2];
#pragma unroll
        for (int s = 0; s < 4; ++s)
#pragma unroll
            for (int fn = 0; fn < 2; ++fn)
                bfr[s][fn] = WpV[(size_t)(it * 4 + s) * 1024 + lg * 256 +
                                 wn * 32 + fn * 16 + lr];
        // cvt + write chunk it into slots it*4..it*4+3 (write-once)
        {
            const int ks1 = it * 4 + sks, ks2 = ks1 + 2;
            bf16x4 w0, w1;
            w0[0] = (__bf16)pa.x; w0[1] = (__bf16)pa.y;
            w0[2] = (__bf16)pa.z; w0[3] = (__bf16)pa.w;
            w1[0] = (__bf16)pb.x; w1[1] = (__bf16)pb.y;
            w1[2] = (__bf16)pb.z; w1[3] = (__bf16)pb.w;
            const int u1 = ks1 * 128 + sgg * 32 + (srow ^ ((ks1 * 4 + sgg) & 7));
            const int u2 = ks2 * 128 + sgg * 32 + (srow ^ ((ks2 * 4 + sgg) & 7));
            *(bf16x4*)((char*)Atile + u1 * 16 + sbh * 8) = w0;
            *(bf16x4*)((char*)Atile + u2 * 16 + sbh * 8) = w1;
        }
        // issue chunk it+2 (stays in flight across the lgkm barrier)
        float4 ra, rb;
        if (it < 6) {
            const float* p = encRow + (it + 2) * 128;
            ra = *(const float4*)p;
            rb = *(const float4*)(p + 64);
        }
        lds_barrier();  // orders ds_writes only; prefetches NOT drained
#pragma unroll
        for (int s = 0; s < 4; ++s) {
            const int ks = it * 4 + s;
#pragma unroll
            for (int fm = 0; fm < 2; ++fm) {
                const int u =
                    ks * 128 + lg * 32 + ((fm * 16 + lr) ^ ((ks * 4 + lg) & 7));
                bf16x8 af = *(const bf16x8*)((const char*)Atile + u * 16);
                acc[fm][0] = __builtin_amdgcn_mfma_f32_16x16x32_bf16(
                    af, bfr[s][0], acc[fm][0], 0, 0, 0);
                acc[fm][1] = __builtin_amdgcn_mfma_f32_16x16x32_bf16(
                    af, bfr[s][1], acc[fm][1], 0, 0, 0);
            }
        }
        pa = qa; pb = qb;
        qa = ra; qb = rb;
    }

    // ---- scores epilogue ----
    float pr[2][4];
#pragma unroll
    for (int fm = 0; fm < 2; ++fm) {
#pragma unroll
        for (int reg = 0; reg < 4; ++reg) {
            float p = fmaf(vv[0], tanh_fast(acc[fm][0][reg] + dp[0]), 0.f);
            p = fmaf(vv[1], tanh_fast(acc[fm][1][reg] + dp[1]), p);
            p += __shfl_xor(p, 1);
            p += __shfl_xor(p, 2);
            p += __shfl_xor(p, 4);
            p += __shfl_xor(p, 8);
            pr[fm][reg] = p;
        }
    }
    __syncthreads();  // all MFMA LDS reads done -> overlay safe
    if (lr == 0) {
#pragma unroll
        for (int fm = 0; fm < 2; ++fm)
#pragma unroll
            for (int reg = 0; reg < 4; ++reg)
                red[wn * 32 + fm * 16 + lg * 4 + reg] = pr[fm][reg];
    }
    __syncthreads();
    if (tid < TCHUNK) {
        float s = 0.f;
#pragma unroll
        for (int w = 0; w < 8; ++w) s += red[w * 32 + tid];
        scores[(t0 + tid) * N_DIM + n] = s;
        if (partial) {
            float m = s;
            m = fmaxf(m, __shfl_xor(m, 1));
            m = fmaxf(m, __shfl_xor(m, 2));
            m = fmaxf(m, __shfl_xor(m, 4));
            m = fmaxf(m, __shfl_xor(m, 8));
            m = fmaxf(m, __shfl_xor(m, 16));
            float w = __expf(s - m);
            float Z = w;
            Z += __shfl_xor(Z, 1);
            Z += __shfl_xor(Z, 2);
            Z += __shfl_xor(Z, 4);
            Z += __shfl_xor(Z, 8);
            Z += __shfl_xor(Z, 16);
            wls[tid] = w;
            if (tid == 0) {
                ms[n * NCHUNK + c] = m;
                zs[n * NCHUNK + c] = Z;
            }
        }
    }
    __syncthreads();

    if (!partial) return;
    // ---- weighted row-sum from LDS tile -> ctx partial ----
    const int cs = tid >> 1, rh = tid & 1;
    const int ks = cs >> 3, gg = (cs >> 1) & 3, bh = cs & 1;
    const int colbase = ks * 32 + gg * 8 + bh * 4;
    f32x4 a4 = (f32x4){0.f, 0.f, 0.f, 0.f};
    if (cs < 250) {  // slots under the red/wls overlay excluded
        const int q = (ks * 4 + gg) & 7;
        const int ubase = ks * 128 + gg * 32;
#pragma unroll 4
        for (int r = rh * 16; r < rh * 16 + 16; ++r) {
            const float w = wls[r];
            bf16x4 ev = *(const bf16x4*)((const char*)Atile +
                                         (ubase + (r ^ q)) * 16 + bh * 8);
            a4[0] = fmaf(w, (float)ev[0], a4[0]);
            a4[1] = fmaf(w, (float)ev[1], a4[1]);
            a4[2] = fmaf(w, (float)ev[2], a4[2]);
            a4[3] = fmaf(w, (float)ev[3], a4[3]);
        }
    } else {  // overlay region: re-read those columns from cache
#pragma unroll 4
        for (int r = rh * 16; r < rh * 16 + 16; ++r) {
            const float w = wls[r];
            float4 ev = *(const float4*)(
                enc + ((size_t)(t0 + r) * N_DIM + n) * E_DIM + colbase);
            a4[0] = fmaf(w, ev.x, a4[0]);
            a4[1] = fmaf(w, ev.y, a4[1]);
            a4[2] = fmaf(w, ev.z, a4[2]);
            a4[3] = fmaf(w, ev.w, a4[3]);
        }
    }
#pragma unroll
    for (int k = 0; k < 4; ++k) a4[k] += __shfl_xor(a4[k], 1);
    if (rh == 0)
        *(f32x4*)(partial + ((size_t)c * N_DIM + n) * E_DIM + colbase) = a4;
}

// ---- combine: per n, flash rescale of 64 chunk partials + alpha ----
__global__ __launch_bounds__(256) void combine_kernel(
    const float* __restrict__ partial, const float* __restrict__ ms,
    const float* __restrict__ zs, const float* __restrict__ scores,
    float* __restrict__ ctx, float* __restrict__ alpha) {
    __shared__ float scale[NCHUNK];
    __shared__ float MZ[2];
    const int n = blockIdx.x;
    const int tid = threadIdx.x;
    if (tid < NCHUNK) {
        float m = ms[n * NCHUNK + tid];
        float M = m;
        M = fmaxf(M, __shfl_xor(M, 1));
        M = fmaxf(M, __shfl_xor(M, 2));
        M = fmaxf(M, __shfl_xor(M, 4));
        M = fmaxf(M, __shfl_xor(M, 8));
        M = fmaxf(M, __shfl_xor(M, 16));
        M = fmaxf(M, __shfl_xor(M, 32));
        float e = __expf(m - M);
        float z = zs[n * NCHUNK + tid] * e;
        float Z = z;
        Z += __shfl_xor(Z, 1);
        Z += __shfl_xor(Z, 2);
        Z += __shfl_xor(Z, 4);
        Z += __shfl_xor(Z, 8);
        Z += __shfl_xor(Z, 16);
        Z += __shfl_xor(Z, 32);
        scale[tid] = e;
        if (tid == 0) {
            MZ[0] = M;
            MZ[1] = Z;
        }
    }
    __syncthreads();
    const float M = MZ[0];
    const float invZ = 1.f / MZ[1];
    f32x4 a4 = (f32x4){0.f, 0.f, 0.f, 0.f};
#pragma unroll 4
    for (int c = 0; c < NCHUNK; ++c) {
        const float s = scale[c] * invZ;
        float4 p = *(const float4*)(partial +
                                    ((size_t)c * N_DIM + n) * E_DIM + tid * 4);
        a4[0] = fmaf(s, p.x, a4[0]);
        a4[1] = fmaf(s, p.y, a4[1]);
        a4[2] = fmaf(s, p.z, a4[2]);
        a4[3] = fmaf(s, p.w, a4[3]);
    }
    *(f32x4*)(ctx + (size_t)n * E_DIM + tid * 4) = a4;
    for (int t = tid; t < T_DIM; t += 256)
        alpha[t * N_DIM + n] = __expf(scores[t * N_DIM + n] - M) * invZ;
}

// ---------------- fallback path (small ws): softmax + fp32 ctx ------------
__global__ __launch_bounds__(256) void softmax_kernel(
    const float* __restrict__ scores, float* __restrict__ alpha) {
    __shared__ float red[256];
    const int n = blockIdx.x;
    const int tid = threadIdx.x;
    float m = -3.4e38f;
    for (int t = tid; t < T_DIM; t += 256)
        m = fmaxf(m, scores[t * N_DIM + n]);
    red[tid] = m;
    __syncthreads();
    for (int s = 128; s; s >>= 1) {
        if (tid < s) red[tid] = fmaxf(red[tid], red[tid + s]);
        __syncthreads();
    }
    m = red[0];
    __syncthreads();
    float sum = 0.f;
    for (int t = tid; t < T_DIM; t += 256)
        sum += expf(scores[t * N_DIM + n] - m);
    red[tid] = sum;
    __syncthreads();
    for (int s = 128; s; s >>= 1) {
        if (tid < s) red[tid] += red[tid + s];
        __syncthreads();
    }
    const float inv = 1.f / red[0];
    for (int t = tid; t < T_DIM; t += 256)
        alpha[t * N_DIM + n] = expf(scores[t * N_DIM + n] - m) * inv;
}

__global__ __launch_bounds__(256) void ctx_f32(const float* __restrict__ enc,
                                               const float* __restrict__ alpha,
                                               float* __restrict__ ctx) {
    const int n = blockIdx.x;
    const int tid = threadIdx.x;
    float4 acc = {0.f, 0.f, 0.f, 0.f};
    for (int t = 0; t < T_DIM; ++t) {
        const float al = alpha[t * N_DIM + n];
        float4 ev = *reinterpret_cast<const float4*>(
            enc + (size_t)(t * N_DIM + n) * E_DIM + tid * 4);
        acc.x = fmaf(al, ev.x, acc.x);
        acc.y = fmaf(al, ev.y, acc.y);
        acc.z = fmaf(al, ev.z, acc.z);
        acc.w = fmaf(al, ev.w, acc.w);
    }
    *reinterpret_cast<float4*>(ctx + (size_t)n * E_DIM + tid * 4) = acc;
}

extern "C" void kernel_launch(void* const* d_in, const int* in_sizes, int n_in,
                              void* d_out, int out_size, void* d_ws,
                              size_t ws_size, hipStream_t stream) {
    const float* enc = (const float*)d_in[0];    // [T,N,E]
    const float* dec_h = (const float*)d_in[1];  // [N,D]
    const float* W_e = (const float*)d_in[2];    // [A,E]
    const float* W_d = (const float*)d_in[3];    // [A,D]
    const float* v = (const float*)d_in[4];      // [1,A]

    float* out = (float*)d_out;
    float* ctx = out;            // 64*1024
    float* alpha = out + 65536;  // 2048*64

    float* ws = (float*)d_ws;
    float* d_proj = ws;                   // 16384 f
    float* scores = ws + 16384;           // 131072 f
    __bf16* Wp = (__bf16*)(ws + 147456);  // 131072 f worth
    float* ms = ws + 278528;              // 4096 f
    float* zs = ws + 282624;              // 4096 f
    float* partial = ws + 286720;         // 64*64*1024 = 4194304 f

    const size_t need =
        (size_t)(286720 + NCHUNK * N_DIM * E_DIM) * sizeof(float);
    const bool big = ws_size >= need;

    prep_kernel<<<192, 256, 0, stream>>>(W_e, dec_h, W_d, Wp, d_proj);
    flash_kernel<<<T_DIM / TCHUNK * N_DIM, 512, 0, stream>>>(
        enc, Wp, d_proj, v, scores, big ? partial : nullptr, ms, zs);
    if (big) {
        combine_kernel<<<N_DIM, 256, 0, stream>>>(partial, ms, zs, scores,
                                                  ctx, alpha);
    } else {
        softmax_kernel<<<N_DIM, 256, 0, stream>>>(scores, alpha);
        ctx_f32<<<N_DIM, 256, 0, stream>>>(enc, alpha, ctx);
    }
}

// Round 8
// 225.202 us; speedup vs baseline: 1.5874x; 1.0143x over previous
//
#include <hip/hip_runtime.h>
#include <math.h>

#define T_DIM 2048
#define N_DIM 64
#define E_DIM 1024
#define A_DIM 256
#define TCHUNK 32
#define NCHUNK (T_DIM / TCHUNK)  // 64

typedef __bf16 bf16x8 __attribute__((ext_vector_type(8)));
typedef __bf16 bf16x4 __attribute__((ext_vector_type(4)));
typedef float f32x4 __attribute__((ext_vector_type(4)));

__device__ __forceinline__ float tanh_fast(float x) {
    float xc = fminf(fmaxf(x, -15.f), 15.f);
    float e = __expf(2.f * xc);
    return (e - 1.f) / (e + 1.f);
}

// LDS-write-ordering barrier that does NOT drain outstanding global loads.
__device__ __forceinline__ void lds_barrier() {
    asm volatile("s_waitcnt lgkmcnt(0)\n\ts_barrier" ::: "memory");
}

// ---- fused prep: blocks 0..127 convert W_e -> bf16 permuted Wp;
//      blocks 128..191 compute d_proj[n][a].
__global__ __launch_bounds__(256) void prep_kernel(
    const float* __restrict__ W_e, const float* __restrict__ dec_h,
    const float* __restrict__ W_d, __bf16* __restrict__ Wp,
    float* __restrict__ d_proj) {
    __shared__ float dec[E_DIM];
    const int tid = threadIdx.x;
    if (blockIdx.x < 128) {
        const int uid = blockIdx.x * 256 + tid;
        const int a = uid >> 7;
        const int c = uid & 127;
        const float4* src = (const float4*)(W_e + (size_t)a * E_DIM + c * 8);
        float4 x0 = src[0], x1 = src[1];
        bf16x8 o;
        o[0] = (__bf16)x0.x; o[1] = (__bf16)x0.y; o[2] = (__bf16)x0.z; o[3] = (__bf16)x0.w;
        o[4] = (__bf16)x1.x; o[5] = (__bf16)x1.y; o[6] = (__bf16)x1.z; o[7] = (__bf16)x1.w;
        *(bf16x8*)(Wp + ((size_t)c * 256 + a) * 8) = o;
    } else {
        const int n = blockIdx.x - 128;
        reinterpret_cast<float4*>(dec)[tid] =
            reinterpret_cast<const float4*>(dec_h + (size_t)n * E_DIM)[tid];
        __syncthreads();
        const float* w = W_d + (size_t)tid * E_DIM;
        float acc = 0.f;
#pragma unroll 4
        for (int e = 0; e < E_DIM; e += 4) {
            float4 wv = *reinterpret_cast<const float4*>(w + e);
            acc = fmaf(wv.x, dec[e], acc);
            acc = fmaf(wv.y, dec[e + 1], acc);
            acc = fmaf(wv.z, dec[e + 2], acc);
            acc = fmaf(wv.w, dec[e + 3], acc);
        }
        d_proj[n * A_DIM + tid] = acc;
    }
}

// ---- flash: block=(n, 32-t chunk), 512 thr = 8 waves (32 a-cols each).
// K=128 per lgkm-barrier. B fragments double-buffered at K=64 granularity so
// their L2 latency hides under MFMA batches; A prefetched 1 chunk ahead.
__global__ __launch_bounds__(512, 4) void flash_kernel(
    const float* __restrict__ enc, const __bf16* __restrict__ Wp,
    const float* __restrict__ dproj, const float* __restrict__ v,
    float* __restrict__ scores, float* __restrict__ partial,
    float* __restrict__ ms, float* __restrict__ zs) {
    __shared__ __align__(16) __bf16 Atile[TCHUNK * E_DIM];  // 64 KB persistent
    float* red = ((float*)Atile) + 16384 - 288;  // tail overlay: red[256]
    float* wls = red + 256;                      // + wls[32]

    const int tid = threadIdx.x;
    const int bid = blockIdx.x;
    const int n = bid & (N_DIM - 1);
    const int c = bid >> 6;
    const int t0 = c * TCHUNK;
    const int wn = tid >> 6;  // wave 0..7 -> a-cols wn*32..+32
    const int lane = tid & 63;
    const int lr = lane & 15, lg = lane >> 4;

    f32x4 acc[2][2];
#pragma unroll
    for (int i = 0; i < 2; ++i)
#pragma unroll
        for (int j = 0; j < 2; ++j) acc[i][j] = (f32x4){0.f, 0.f, 0.f, 0.f};

    float vv[2], dp[2];
#pragma unroll
    for (int fn = 0; fn < 2; ++fn) {
        const int a = wn * 32 + fn * 16 + lr;
        vv[fn] = v[a];
        dp[fn] = dproj[n * A_DIM + a];
    }

    // staging map: thread -> (row 0..31, sg 0..15); per iter loads cols
    // it*128+sg*4 and it*128+64+sg*4 of its row.
    const int srow = tid >> 4, sg = tid & 15;
    const int sgg = (sg & 7) >> 1, sbh = sg & 1;
    const int sks = sg >> 3;
    const float* encRow =
        enc + ((size_t)(t0 + srow) * N_DIM + n) * E_DIM + sg * 4;
    const bf16x8* WpV = (const bf16x8*)Wp;
    const int bfoff = lg * 256 + wn * 32 + lr;  // + fn*16 + ks*1024

    // prologue: A chunk 0 in flight; bA = B frags for ks {0,1}
    float4 pa = *(const float4*)encRow;
    float4 pb = *(const float4*)(encRow + 64);
    bf16x8 bA[2][2];
#pragma unroll
    for (int s = 0; s < 2; ++s)
#pragma unroll
        for (int fn = 0; fn < 2; ++fn)
            bA[s][fn] = WpV[(size_t)s * 1024 + bfoff + fn * 16];

#pragma unroll
    for (int it = 0; it < 8; ++it) {
        // (1) load bB = B frags for ks {4it+2, 4it+3} (consumed after ~600cyc)
        bf16x8 bB[2][2];
#pragma unroll
        for (int s = 0; s < 2; ++s)
#pragma unroll
            for (int fn = 0; fn < 2; ++fn)
                bB[s][fn] =
                    WpV[(size_t)(it * 4 + 2 + s) * 1024 + bfoff + fn * 16];
        // (2) cvt + write A chunk it into slots it*4..it*4+3 (write-once)
        {
            const int ks1 = it * 4 + sks, ks2 = ks1 + 2;
            bf16x4 w0, w1;
            w0[0] = (__bf16)pa.x; w0[1] = (__bf16)pa.y;
            w0[2] = (__bf16)pa.z; w0[3] = (__bf16)pa.w;
            w1[0] = (__bf16)pb.x; w1[1] = (__bf16)pb.y;
            w1[2] = (__bf16)pb.z; w1[3] = (__bf16)pb.w;
            const int u1 = ks1 * 128 + sgg * 32 + (srow ^ ((ks1 * 4 + sgg) & 7));
            const int u2 = ks2 * 128 + sgg * 32 + (srow ^ ((ks2 * 4 + sgg) & 7));
            *(bf16x4*)((char*)Atile + u1 * 16 + sbh * 8) = w0;
            *(bf16x4*)((char*)Atile + u2 * 16 + sbh * 8) = w1;
        }
        // (3) issue A chunk it+1 (stays in flight across the barrier)
        float4 ra, rb;
        if (it < 7) {
            const float* p = encRow + (it + 1) * 128;
            ra = *(const float4*)p;
            rb = *(const float4*)(p + 64);
        }
        lds_barrier();  // orders ds_writes only; global loads NOT drained
        // (4) MFMA first half: ks {4it, 4it+1} with bA (in regs since last it)
#pragma unroll
        for (int s = 0; s < 2; ++s) {
            const int ks = it * 4 + s;
#pragma unroll
            for (int fm = 0; fm < 2; ++fm) {
                const int u =
                    ks * 128 + lg * 32 + ((fm * 16 + lr) ^ ((ks * 4 + lg) & 7));
                bf16x8 af = *(const bf16x8*)((const char*)Atile + u * 16);
                acc[fm][0] = __builtin_amdgcn_mfma_f32_16x16x32_bf16(
                    af, bA[s][0], acc[fm][0], 0, 0, 0);
                acc[fm][1] = __builtin_amdgcn_mfma_f32_16x16x32_bf16(
                    af, bA[s][1], acc[fm][1], 0, 0, 0);
            }
        }
        // (5) load bA for next iter: ks {4(it+1), 4(it+1)+1}
        bf16x8 bAn[2][2];
        if (it < 7) {
#pragma unroll
            for (int s = 0; s < 2; ++s)
#pragma unroll
                for (int fn = 0; fn < 2; ++fn)
                    bAn[s][fn] =
                        WpV[(size_t)((it + 1) * 4 + s) * 1024 + bfoff + fn * 16];
        }
        // (6) MFMA second half: ks {4it+2, 4it+3} with bB
#pragma unroll
        for (int s = 0; s < 2; ++s) {
            const int ks = it * 4 + 2 + s;
#pragma unroll
            for (int fm = 0; fm < 2; ++fm) {
                const int u =
                    ks * 128 + lg * 32 + ((fm * 16 + lr) ^ ((ks * 4 + lg) & 7));
                bf16x8 af = *(const bf16x8*)((const char*)Atile + u * 16);
                acc[fm][0] = __builtin_amdgcn_mfma_f32_16x16x32_bf16(
                    af, bB[s][0], acc[fm][0], 0, 0, 0);
                acc[fm][1] = __builtin_amdgcn_mfma_f32_16x16x32_bf16(
                    af, bB[s][1], acc[fm][1], 0, 0, 0);
            }
        }
        // rotate (fully unrolled -> SSA renames, no copies in final ISA)
        pa = ra; pb = rb;
#pragma unroll
        for (int s = 0; s < 2; ++s)
#pragma unroll
            for (int fn = 0; fn < 2; ++fn) bA[s][fn] = bAn[s][fn];
    }

    // ---- scores epilogue ----
    float pr[2][4];
#pragma unroll
    for (int fm = 0; fm < 2; ++fm) {
#pragma unroll
        for (int reg = 0; reg < 4; ++reg) {
            float p = fmaf(vv[0], tanh_fast(acc[fm][0][reg] + dp[0]), 0.f);
            p = fmaf(vv[1], tanh_fast(acc[fm][1][reg] + dp[1]), p);
            p += __shfl_xor(p, 1);
            p += __shfl_xor(p, 2);
            p += __shfl_xor(p, 4);
            p += __shfl_xor(p, 8);
            pr[fm][reg] = p;
        }
    }
    __syncthreads();  // all MFMA LDS reads done -> overlay safe
    if (lr == 0) {
#pragma unroll
        for (int fm = 0; fm < 2; ++fm)
#pragma unroll
            for (int reg = 0; reg < 4; ++reg)
                red[wn * 32 + fm * 16 + lg * 4 + reg] = pr[fm][reg];
    }
    __syncthreads();
    if (tid < TCHUNK) {
        float s = 0.f;
#pragma unroll
        for (int w = 0; w < 8; ++w) s += red[w * 32 + tid];
        scores[(t0 + tid) * N_DIM + n] = s;
        if (partial) {
            float m = s;
            m = fmaxf(m, __shfl_xor(m, 1));
            m = fmaxf(m, __shfl_xor(m, 2));
            m = fmaxf(m, __shfl_xor(m, 4));
            m = fmaxf(m, __shfl_xor(m, 8));
            m = fmaxf(m, __shfl_xor(m, 16));
            float w = __expf(s - m);
            float Z = w;
            Z += __shfl_xor(Z, 1);
            Z += __shfl_xor(Z, 2);
            Z += __shfl_xor(Z, 4);
            Z += __shfl_xor(Z, 8);
            Z += __shfl_xor(Z, 16);
            wls[tid] = w;
            if (tid == 0) {
                ms[n * NCHUNK + c] = m;
                zs[n * NCHUNK + c] = Z;
            }
        }
    }
    __syncthreads();

    if (!partial) return;
    // ---- weighted row-sum from LDS tile -> ctx partial ----
    const int cs = tid >> 1, rh = tid & 1;
    const int ks = cs >> 3, gg = (cs >> 1) & 3, bh = cs & 1;
    const int colbase = ks * 32 + gg * 8 + bh * 4;
    f32x4 a4 = (f32x4){0.f, 0.f, 0.f, 0.f};
    if (cs < 250) {  // slots under the red/wls overlay excluded
        const int q = (ks * 4 + gg) & 7;
        const int ubase = ks * 128 + gg * 32;
#pragma unroll 4
        for (int r = rh * 16; r < rh * 16 + 16; ++r) {
            const float w = wls[r];
            bf16x4 ev = *(const bf16x4*)((const char*)Atile +
                                         (ubase + (r ^ q)) * 16 + bh * 8);
            a4[0] = fmaf(w, (float)ev[0], a4[0]);
            a4[1] = fmaf(w, (float)ev[1], a4[1]);
            a4[2] = fmaf(w, (float)ev[2], a4[2]);
            a4[3] = fmaf(w, (float)ev[3], a4[3]);
        }
    } else {  // overlay region: re-read those columns from cache
#pragma unroll 4
        for (int r = rh * 16; r < rh * 16 + 16; ++r) {
            const float w = wls[r];
            float4 ev = *(const float4*)(
                enc + ((size_t)(t0 + r) * N_DIM + n) * E_DIM + colbase);
            a4[0] = fmaf(w, ev.x, a4[0]);
            a4[1] = fmaf(w, ev.y, a4[1]);
            a4[2] = fmaf(w, ev.z, a4[2]);
            a4[3] = fmaf(w, ev.w, a4[3]);
        }
    }
#pragma unroll
    for (int k = 0; k < 4; ++k) a4[k] += __shfl_xor(a4[k], 1);
    if (rh == 0)
        *(f32x4*)(partial + ((size_t)c * N_DIM + n) * E_DIM + colbase) = a4;
}

// ---- combine: per n, flash rescale of 64 chunk partials + alpha ----
__global__ __launch_bounds__(256) void combine_kernel(
    const float* __restrict__ partial, const float* __restrict__ ms,
    const float* __restrict__ zs, const float* __restrict__ scores,
    float* __restrict__ ctx, float* __restrict__ alpha) {
    __shared__ float scale[NCHUNK];
    __shared__ float MZ[2];
    const int n = blockIdx.x;
    const int tid = threadIdx.x;
    if (tid < NCHUNK) {
        float m = ms[n * NCHUNK + tid];
        float M = m;
        M = fmaxf(M, __shfl_xor(M, 1));
        M = fmaxf(M, __shfl_xor(M, 2));
        M = fmaxf(M, __shfl_xor(M, 4));
        M = fmaxf(M, __shfl_xor(M, 8));
        M = fmaxf(M, __shfl_xor(M, 16));
        M = fmaxf(M, __shfl_xor(M, 32));
        float e = __expf(m - M);
        float z = zs[n * NCHUNK + tid] * e;
        float Z = z;
        Z += __shfl_xor(Z, 1);
        Z += __shfl_xor(Z, 2);
        Z += __shfl_xor(Z, 4);
        Z += __shfl_xor(Z, 8);
        Z += __shfl_xor(Z, 16);
        Z += __shfl_xor(Z, 32);
        scale[tid] = e;
        if (tid == 0) {
            MZ[0] = M;
            MZ[1] = Z;
        }
    }
    __syncthreads();
    const float M = MZ[0];
    const float invZ = 1.f / MZ[1];
    f32x4 a4 = (f32x4){0.f, 0.f, 0.f, 0.f};
#pragma unroll 4
    for (int c = 0; c < NCHUNK; ++c) {
        const float s = scale[c] * invZ;
        float4 p = *(const float4*)(partial +
                                    ((size_t)c * N_DIM + n) * E_DIM + tid * 4);
        a4[0] = fmaf(s, p.x, a4[0]);
        a4[1] = fmaf(s, p.y, a4[1]);
        a4[2] = fmaf(s, p.z, a4[2]);
        a4[3] = fmaf(s, p.w, a4[3]);
    }
    *(f32x4*)(ctx + (size_t)n * E_DIM + tid * 4) = a4;
    for (int t = tid; t < T_DIM; t += 256)
        alpha[t * N_DIM + n] = __expf(scores[t * N_DIM + n] - M) * invZ;
}

// ---------------- fallback path (small ws): softmax + fp32 ctx ------------
__global__ __launch_bounds__(256) void softmax_kernel(
    const float* __restrict__ scores, float* __restrict__ alpha) {
    __shared__ float red[256];
    const int n = blockIdx.x;
    const int tid = threadIdx.x;
    float m = -3.4e38f;
    for (int t = tid; t < T_DIM; t += 256)
        m = fmaxf(m, scores[t * N_DIM + n]);
    red[tid] = m;
    __syncthreads();
    for (int s = 128; s; s >>= 1) {
        if (tid < s) red[tid] = fmaxf(red[tid], red[tid + s]);
        __syncthreads();
    }
    m = red[0];
    __syncthreads();
    float sum = 0.f;
    for (int t = tid; t < T_DIM; t += 256)
        sum += expf(scores[t * N_DIM + n] - m);
    red[tid] = sum;
    __syncthreads();
    for (int s = 128; s; s >>= 1) {
        if (tid < s) red[tid] += red[tid + s];
        __syncthreads();
    }
    const float inv = 1.f / red[0];
    for (int t = tid; t < T_DIM; t += 256)
        alpha[t * N_DIM + n] = expf(scores[t * N_DIM + n] - m) * inv;
}

__global__ __launch_bounds__(256) void ctx_f32(const float* __restrict__ enc,
                                               const float* __restrict__ alpha,
                                               float* __restrict__ ctx) {
    const int n = blockIdx.x;
    const int tid = threadIdx.x;
    float4 acc = {0.f, 0.f, 0.f, 0.f};
    for (int t = 0; t < T_DIM; ++t) {
        const float al = alpha[t * N_DIM + n];
        float4 ev = *reinterpret_cast<const float4*>(
            enc + (size_t)(t * N_DIM + n) * E_DIM + tid * 4);
        acc.x = fmaf(al, ev.x, acc.x);
        acc.y = fmaf(al, ev.y, acc.y);
        acc.z = fmaf(al, ev.z, acc.z);
        acc.w = fmaf(al, ev.w, acc.w);
    }
    *reinterpret_cast<float4*>(ctx + (size_t)n * E_DIM + tid * 4) = acc;
}

extern "C" void kernel_launch(void* const* d_in, const int* in_sizes, int n_in,
                              void* d_out, int out_size, void* d_ws,
                              size_t ws_size, hipStream_t stream) {
    const float* enc = (const float*)d_in[0];    // [T,N,E]
    const float* dec_h = (const float*)d_in[1];  // [N,D]
    const float* W_e = (const float*)d_in[2];    // [A,E]
    const float* W_d = (const float*)d_in[3];    // [A,D]
    const float* v = (const float*)d_in[4];      // [1,A]

    float* out = (float*)d_out;
    float* ctx = out;            // 64*1024
    float* alpha = out + 65536;  // 2048*64

    float* ws = (float*)d_ws;
    float* d_proj = ws;                   // 16384 f
    float* scores = ws + 16384;           // 131072 f
    __bf16* Wp = (__bf16*)(ws + 147456);  // 131072 f worth
    float* ms = ws + 278528;              // 4096 f
    float* zs = ws + 282624;              // 4096 f
    float* partial = ws + 286720;         // 64*64*1024 = 4194304 f

    const size_t need =
        (size_t)(286720 + NCHUNK * N_DIM * E_DIM) * sizeof(float);
    const bool big = ws_size >= need;

    prep_kernel<<<192, 256, 0, stream>>>(W_e, dec_h, W_d, Wp, d_proj);
    flash_kernel<<<T_DIM / TCHUNK * N_DIM, 512, 0, stream>>>(
        enc, Wp, d_proj, v, scores, big ? partial : nullptr, ms, zs);
    if (big) {
        combine_kernel<<<N_DIM, 256, 0, stream>>>(partial, ms, zs, scores,
                                                  ctx, alpha);
    } else {
        softmax_kernel<<<N_DIM, 256, 0, stream>>>(scores, alpha);
        ctx_f32<<<N_DIM, 256, 0, stream>>>(enc, alpha, ctx);
    }
}